// Round 6
// baseline (37.215 us; speedup 1.0000x reference)
//
#include <hip/hip_runtime.h>
#include <math.h>

// ---- Problem constants (from reference) ----
#define KPT 9
#define NB 16
#define NH 76
#define NW 76
#define MAX_T 50
#define NCH 20                 // NA*(2K+1+NC) = 20
#define NUM_LABELS 21          // 2K+3
#define CELLS (NH*NW)          // 5776
#define IM_W 640.0f
#define IM_H 480.0f
#define SX (IM_W/(float)NW)    // px per cell, x
#define SY (IM_H/(float)NH)    // px per cell, y
#define DIST_THRESH 30.0f
#define D2_THRESH (DIST_THRESH*DIST_THRESH)
#define SIL_THRESH 0.6f
#define OBJECT_SCALE 5.0f
#define NOOBJECT_SCALE 0.1f
#define PRETRAIN_EPOCHS 15
// c = (exp(2*(1-d/30)) - 1) / (e^2 - 1), mean over K=9
#define E2M1 6.3890560989306495f          // e^2 - 1
#define CNORM (1.0f/(E2M1*9.0f))
// curconf > SIL_THRESH  <=>  raw csum > SIL_THRESH*(e^2-1)*9
#define CURMAX_BREAK (SIL_THRESH * E2M1 * 9.0f)
// csum <= cnt_close*(e^2-1); csum > BREAK requires cnt_close >= 6
#define CNT_MIN 6

#define TSPLIT 8               // target-loop split across 8 waves
#define CPB 64                 // cells per block (one per lane)
#define NTHREADS (TSPLIT*64)

// ---- d_ws layout ----
// float region: per (b,t) record of TREC floats:
//   [0..17]  gt pixel coords (x0,y0,...,x8,y8), [18..19] pad (1e18 = never close)
//   [20..37] txy residuals (tx0,ty0,...,tx8,ty8)
//   [38]     tconf     [39] pad
// then: int W[NB][CELLS] winner table (-1 = none), then int nvA[NB]
#define TREC 40
#define GT_FLOATS (NB*MAX_T*TREC)   // 32000 floats

__device__ __forceinline__ float sigmoidf_(float x) {
    return 1.0f / (1.0f + __expf(-x));
}

// ---- kernel 1: per-target precompute + winner table + out zero (16 blocks) ----
__global__ void precompute_kernel(const float* __restrict__ output,
                                  const float* __restrict__ target,
                                  float* __restrict__ wsf,
                                  int* __restrict__ W,
                                  int* __restrict__ nvA,
                                  float* __restrict__ d_out)
{
    const int b   = blockIdx.x;
    const int tid = threadIdx.x;
    const float* tgb = target + (size_t)b * MAX_T * NUM_LABELS;

    // validity prefix via uniform 64-lane ballot (no LDS needed)
    float v1 = (tid < MAX_T) ? tgb[tid * NUM_LABELS + 1] : 1.0f;
    unsigned long long zm = __ballot(v1 == 0.0f);
    int nv = (zm == 0ULL) ? MAX_T : (__ffsll((long long)zm) - 1);
    if (nv > MAX_T) nv = MAX_T;

    // zero this batch's winner table
    for (int i = tid; i < CELLS; i += 64) W[(size_t)b * CELLS + i] = -1;

    __shared__ int s_cellA[MAX_T];

    if (tid < MAX_T) {
        const float* row = tgb + tid * NUM_LABELS;
        float gx0 = row[1] * (float)NW;
        float gy0 = row[2] * (float)NH;
        int gi0 = (int)gx0;               // truncation == astype(int32)
        int gj0 = (int)gy0;
        int cellt = gj0 * NW + gi0;
        int cellc = min(max(cellt, 0), CELLS - 1);
        int hc = cellc / NW, wc = cellc % NW;
        const float* ob = output + (size_t)b * NCH * CELLS + cellc;
        float* rec = wsf + ((size_t)b * MAX_T + tid) * TREC;
        float csum = 0.0f;
        #pragma unroll
        for (int k = 0; k < KPT; ++k) {
            float gxk = row[1 + 2*k];
            float gyk = row[2 + 2*k];
            float gxp = gxk * IM_W;
            float gyp = gyk * IM_H;
            rec[2*k]      = gxp;
            rec[2*k + 1]  = gyp;
            rec[20 + 2*k] = gxk * (float)NW - (float)gi0;
            rec[21 + 2*k] = gyk * (float)NH - (float)gj0;
            float xo = ob[(2*k) * CELLS];
            float yo = ob[(2*k + 1) * CELLS];
            if (k == 0) { xo = sigmoidf_(xo); yo = sigmoidf_(yo); }
            float dx = gxp - (xo + (float)wc) * SX;
            float dy = gyp - (yo + (float)hc) * SY;
            float d2 = dx*dx + dy*dy;
            if (d2 < D2_THRESH)
                csum += __expf(2.0f - sqrtf(d2) * (2.0f / DIST_THRESH)) - 1.0f;
        }
        rec[18] = 1e18f; rec[19] = 1e18f;     // pad keypoint: never close
        rec[38] = csum * CNORM;               // tconf
        rec[39] = 0.0f;
        bool ok = (gi0 >= 0 && gi0 < NW && gj0 >= 0 && gj0 < NH) && (tid < nv);
        s_cellA[tid] = ok ? cellt : -1;
    }
    __syncthreads();
    if (tid == 0) {
        // ascending t: last valid t wins == reference scatter .set semantics
        for (int t = 0; t < nv; ++t) {
            int c = s_cellA[t];
            if (c >= 0) W[(size_t)b * CELLS + c] = t;
        }
        nvA[b] = nv;
        if (b == 0) d_out[0] = 0.0f;
    }
}

// ---- kernel 2: main loss ----
__launch_bounds__(NTHREADS)
__global__ void region_loss_kernel(const float* __restrict__ output,
                                   const float* __restrict__ wsf,
                                   const int* __restrict__ W,
                                   const int* __restrict__ nvA,
                                   const int* __restrict__ epoch_p,
                                   float* __restrict__ d_out)
{
    const int tid  = threadIdx.x;
    const int wave = tid >> 6;       // 0..7 = target chunk
    const int cl   = tid & 63;       // cell within block
    const int b    = blockIdx.y;
    const int cell = blockIdx.x * CPB + cl;
    const bool live = (cell < CELLS);

    __shared__ float s_sil[TSPLIT][CPB];

    const int nv = nvA[b];

    float pxs[KPT], pys[KPT];
    float sil = 0.0f;
    if (live) {
        const int h = cell / NW;
        const int w = cell - h * NW;
        const float* ob = output + (size_t)b * NCH * CELLS + cell;
        #pragma unroll
        for (int k = 0; k < KPT; ++k) {
            float xo = ob[(2*k) * CELLS];
            float yo = ob[(2*k + 1) * CELLS];
            if (k == 0) { xo = sigmoidf_(xo); yo = sigmoidf_(yo); }
            pxs[k] = (xo + (float)w) * SX;
            pys[k] = (yo + (float)h) * SY;
        }

        // software-pipelined t-loop: prefetch t+TSPLIT from L2 while computing t
        const float* base = wsf + (size_t)b * MAX_T * TREC;
        float4 c0 = {0,0,0,0}, c1 = c0, c2 = c0, c3 = c0, c4 = c0;
        float4 n0 = c0, n1 = c0, n2 = c0, n3 = c0, n4 = c0;
        int t = wave;
        if (t < nv) {
            const float4* g = (const float4*)(base + t * TREC);
            c0 = g[0]; c1 = g[1]; c2 = g[2]; c3 = g[3]; c4 = g[4];
        }
        for (; t < nv; t += TSPLIT) {
            const int tn = t + TSPLIT;
            if (tn < nv) {
                const float4* g = (const float4*)(base + tn * TREC);
                n0 = g[0]; n1 = g[1]; n2 = g[2]; n3 = g[3]; n4 = g[4];
            }
            int cnt = 0;
            #define KP(gx, gy, k) { \
                float dx = (gx) - pxs[k]; \
                float dy = (gy) - pys[k]; \
                float d2 = __builtin_fmaf(dx, dx, dy*dy); \
                cnt += (d2 < D2_THRESH) ? 1 : 0; }
            KP(c0.x, c0.y, 0) KP(c0.z, c0.w, 1)
            KP(c1.x, c1.y, 2) KP(c1.z, c1.w, 3)
            KP(c2.x, c2.y, 4) KP(c2.z, c2.w, 5)
            KP(c3.x, c3.y, 6) KP(c3.z, c3.w, 7)
            KP(c4.x, c4.y, 8)
            #undef KP
            // csum can exceed CURMAX_BREAK only if >= 6 kpts close.
            // Exec-masked rare path (P ~ 1e-10 per pair): exact evaluation.
            if (cnt >= CNT_MIN) {
                float csum = 0.0f;
                #define KQ(gx, gy, k) { \
                    float dx = (gx) - pxs[k]; \
                    float dy = (gy) - pys[k]; \
                    float d2 = __builtin_fmaf(dx, dx, dy*dy); \
                    if (d2 < D2_THRESH) \
                        csum += __expf(2.0f - sqrtf(d2) * (2.0f / DIST_THRESH)) - 1.0f; }
                KQ(c0.x, c0.y, 0) KQ(c0.z, c0.w, 1)
                KQ(c1.x, c1.y, 2) KQ(c1.z, c1.w, 3)
                KQ(c2.x, c2.y, 4) KQ(c2.z, c2.w, 5)
                KQ(c3.x, c3.y, 6) KQ(c3.z, c3.w, 7)
                KQ(c4.x, c4.y, 8)
                #undef KQ
                if (csum > CURMAX_BREAK) sil = 1.0f;
            }
            c0 = n0; c1 = n1; c2 = n2; c3 = n3; c4 = n4;
        }
    }
    s_sil[wave][cl] = sil;
    __syncthreads();

    // ---- phase 2: wave 0 combines + computes loss ----
    float contrib = 0.0f;
    if (wave == 0 && live) {
        float sl = 0.0f;
        #pragma unroll
        for (int wv = 0; wv < TSPLIT; ++wv) sl = fmaxf(sl, s_sil[wv][cl]);
        const int wn = W[(size_t)b * CELLS + cell];
        const int h = cell / NW;
        const int w = cell - h * NW;
        const float* ob = output + (size_t)b * NCH * CELLS + cell;
        const float conf = sigmoidf_(ob[2*KPT * CELLS]);

        float cmask, tconf;
        if (wn >= 0) {
            const float* rec = wsf + ((size_t)b * MAX_T + wn) * TREC;
            cmask = OBJECT_SCALE;
            tconf = rec[38];
            #pragma unroll
            for (int k = 0; k < KPT; ++k) {
                // recover raw (xs,ys) from pixel preds: xo = px/SX - w
                float xo = pxs[k] * (1.0f/SX) - (float)w;
                float yo = pys[k] * (1.0f/SY) - (float)h;
                float dxv = xo - rec[20 + 2*k];
                float dyv = yo - rec[21 + 2*k];
                contrib += 0.5f * (dxv*dxv + dyv*dyv);   // COORD_SCALE = 1
            }
        } else {
            cmask = (sl > 0.0f) ? 0.0f : NOOBJECT_SCALE;
            tconf = 0.0f;
        }
        if (epoch_p[0] > PRETRAIN_EPOCHS) {
            float d = conf - tconf;
            contrib += 0.5f * cmask * d * d;
        }
    }

    // ---- wave-0 shuffle reduction + one atomic per block ----
    if (wave == 0) {
        #pragma unroll
        for (int off = 32; off > 0; off >>= 1)
            contrib += __shfl_down(contrib, off);
        if (cl == 0) atomicAdd(d_out, contrib);
    }
}

extern "C" void kernel_launch(void* const* d_in, const int* in_sizes, int n_in,
                              void* d_out, int out_size, void* d_ws, size_t ws_size,
                              hipStream_t stream) {
    const float* output = (const float*)d_in[0];
    const float* target = (const float*)d_in[1];
    const int*   epoch  = (const int*)d_in[2];
    float* out = (float*)d_out;

    float* wsf = (float*)d_ws;
    int*   W   = (int*)(wsf + GT_FLOATS);
    int*   nvA = W + (size_t)NB * CELLS;

    precompute_kernel<<<NB, 64, 0, stream>>>(output, target, wsf, W, nvA, out);

    dim3 grid((CELLS + CPB - 1) / CPB, NB);
    region_loss_kernel<<<grid, NTHREADS, 0, stream>>>(output, wsf, W, nvA, epoch, out);
}

// Round 7
// 34.749 us; speedup vs baseline: 1.0710x; 1.0710x over previous
//
#include <hip/hip_runtime.h>
#include <math.h>

// ---- Problem constants (from reference) ----
#define KPT 9
#define NB 16
#define NH 76
#define NW 76
#define MAX_T 50
#define NCH 20                 // NA*(2K+1+NC) = 20
#define NUM_LABELS 21          // 2K+3
#define CELLS (NH*NW)          // 5776
#define IM_W 640.0f
#define IM_H 480.0f
#define SX (IM_W/(float)NW)    // px per cell, x
#define SY (IM_H/(float)NH)    // px per cell, y
#define DIST_THRESH 30.0f
#define D2_THRESH (DIST_THRESH*DIST_THRESH)
#define SIL_THRESH 0.6f
#define OBJECT_SCALE 5.0f
#define NOOBJECT_SCALE 0.1f
#define PRETRAIN_EPOCHS 15
// c = (exp(2*(1-d/30)) - 1) / (e^2 - 1), mean over K=9
#define E2M1 6.3890560989306495f          // e^2 - 1
#define CNORM (1.0f/(E2M1*9.0f))
// curconf > SIL_THRESH  <=>  raw csum > SIL_THRESH*(e^2-1)*9
#define CURMAX_BREAK (SIL_THRESH * E2M1 * 9.0f)
// csum <= cnt_close*(e^2-1); csum > BREAK requires cnt_close >= 6
#define CNT_MIN 6

#define TSPLIT 8               // target-loop split across 8 waves
#define CPB 64                 // cells per block (one per lane)
#define NTHREADS (TSPLIT*64)
#define NCH_USED 19            // channels 0..18 (18 coords + conf)

// ---- d_ws layout ----
// float region: per (b,t) record of TREC floats:
//   [0..17]  gt pixel coords (x0,y0,...,x8,y8), [18..19] pad (1e18 = never close)
//   [20..37] txy residuals, [38] tconf, [39] pad
// then: int W[NB][CELLS] winner table (-1 = none), then int nvA[NB]
#define TREC 40
#define GT_FLOATS (NB*MAX_T*TREC)

__device__ __forceinline__ float sigmoidf_(float x) {
    return 1.0f / (1.0f + __expf(-x));
}

// ---- kernel 1: per-target precompute, parallel over (t,k) ----
__launch_bounds__(512)
__global__ void precompute_kernel(const float* __restrict__ output,
                                  const float* __restrict__ target,
                                  float* __restrict__ wsf,
                                  int* __restrict__ W,
                                  int* __restrict__ nvA,
                                  float* __restrict__ d_out)
{
    const int b   = blockIdx.x;
    const int tid = threadIdx.x;
    const float* tgb = target + (size_t)b * MAX_T * NUM_LABELS;

    __shared__ int   s_nv;
    __shared__ float s_csum[MAX_T];
    __shared__ int   s_cellA[MAX_T];

    if (tid < 64) {
        float v1 = (tid < MAX_T) ? tgb[tid * NUM_LABELS + 1] : 1.0f;
        unsigned long long zm = __ballot(v1 == 0.0f);
        if (tid == 0) {
            int fz = (zm == 0ULL) ? MAX_T : (__ffsll((long long)zm) - 1);
            s_nv = fz < MAX_T ? fz : MAX_T;
        }
    }
    if (tid < MAX_T) s_csum[tid] = 0.0f;
    // zero winner table for this batch
    for (int i = tid; i < CELLS; i += 512) W[(size_t)b * CELLS + i] = -1;
    __syncthreads();

    // parallel over 450 (t,k) units
    if (tid < MAX_T * KPT) {
        const int t = tid / KPT;
        const int k = tid - t * KPT;
        const float* row = tgb + t * NUM_LABELS;
        float gxk = row[1 + 2*k];
        float gyk = row[2 + 2*k];
        int gi0 = (int)(row[1] * (float)NW);
        int gj0 = (int)(row[2] * (float)NH);
        float* rec = wsf + ((size_t)b * MAX_T + t) * TREC;
        float gxp = gxk * IM_W;
        float gyp = gyk * IM_H;
        rec[2*k]      = gxp;
        rec[2*k + 1]  = gyp;
        rec[20 + 2*k] = gxk * (float)NW - (float)gi0;
        rec[21 + 2*k] = gyk * (float)NH - (float)gj0;
        int cellc = min(max(gj0 * NW + gi0, 0), CELLS - 1);
        int hc = cellc / NW, wc = cellc - hc * NW;
        const float* ob = output + (size_t)b * NCH * CELLS + cellc;
        float xo = ob[(2*k) * CELLS];
        float yo = ob[(2*k + 1) * CELLS];
        if (k == 0) { xo = sigmoidf_(xo); yo = sigmoidf_(yo); }
        float dx = gxp - (xo + (float)wc) * SX;
        float dy = gyp - (yo + (float)hc) * SY;
        float d2 = dx*dx + dy*dy;
        if (d2 < D2_THRESH)
            atomicAdd(&s_csum[t], __expf(2.0f - sqrtf(d2) * (2.0f / DIST_THRESH)) - 1.0f);
    }
    __syncthreads();

    if (tid < MAX_T) {
        const float* row = tgb + tid * NUM_LABELS;
        int gi0 = (int)(row[1] * (float)NW);
        int gj0 = (int)(row[2] * (float)NH);
        float* rec = wsf + ((size_t)b * MAX_T + tid) * TREC;
        rec[18] = 1e18f; rec[19] = 1e18f;     // pad keypoint: never close
        rec[38] = s_csum[tid] * CNORM;        // tconf
        rec[39] = 0.0f;
        bool ok = (gi0 >= 0 && gi0 < NW && gj0 >= 0 && gj0 < NH) && (tid < s_nv);
        s_cellA[tid] = ok ? (gj0 * NW + gi0) : -1;
    }
    __syncthreads();
    if (tid == 0) {
        // ascending t: last valid t wins == reference scatter .set semantics
        for (int t = 0; t < s_nv; ++t) {
            int c = s_cellA[t];
            if (c >= 0) W[(size_t)b * CELLS + c] = t;
        }
        nvA[b] = s_nv;
        if (b == 0) d_out[0] = 0.0f;
    }
}

// ---- kernel 2: main loss, fully LDS-staged ----
__launch_bounds__(NTHREADS)
__global__ void region_loss_kernel(const float* __restrict__ output,
                                   const float* __restrict__ wsf,
                                   const int* __restrict__ W,
                                   const int* __restrict__ nvA,
                                   const int* __restrict__ epoch_p,
                                   float* __restrict__ d_out)
{
    const int tid  = threadIdx.x;
    const int wave = tid >> 6;       // 0..7 = target chunk
    const int cl   = tid & 63;       // cell within block
    const int b    = blockIdx.y;
    const int cellb = blockIdx.x * CPB;
    const int cell = cellb + cl;
    const bool live = (cell < CELLS);

    __shared__ float  s_ch[NCH_USED][CPB];   // staged channel slab
    __shared__ float4 s_gt4[MAX_T][5];       // staged gt px coords
    __shared__ float  s_sil[TSPLIT][CPB];

    // ---- cooperative staging (coalesced) ----
    {
        const float* obase = output + (size_t)b * NCH * CELLS + cellb;
        for (int idx = tid; idx < NCH_USED * CPB; idx += NTHREADS) {
            int ch = idx >> 6, c = idx & 63;
            s_ch[ch][c] = (cellb + c < CELLS) ? obase[(size_t)ch * CELLS + c] : 0.0f;
        }
        const float4* gbase = (const float4*)(wsf + (size_t)b * MAX_T * TREC);
        for (int idx = tid; idx < MAX_T * 5; idx += NTHREADS) {
            int t = idx / 5, q = idx - t * 5;
            s_gt4[t][q] = gbase[t * (TREC/4) + q];
        }
    }
    __syncthreads();

    const int nv = nvA[b];
    const int h = cell / NW;
    const int w = cell - h * NW;

    // per-lane predicted px coords from LDS (redundant per wave, zero traffic)
    float pxs[KPT], pys[KPT];
    #pragma unroll
    for (int k = 0; k < KPT; ++k) {
        float xo = s_ch[2*k][cl];
        float yo = s_ch[2*k + 1][cl];
        if (k == 0) { xo = sigmoidf_(xo); yo = sigmoidf_(yo); }
        pxs[k] = (xo + (float)w) * SX;
        pys[k] = (yo + (float)h) * SY;
    }

    float sil = 0.0f;
    if (live) {
        for (int t = wave; t < nv; t += TSPLIT) {
            float4 q0 = s_gt4[t][0];   // broadcast ds_read_b128, no conflict
            float4 q1 = s_gt4[t][1];
            float4 q2 = s_gt4[t][2];
            float4 q3 = s_gt4[t][3];
            float4 q4 = s_gt4[t][4];
            int cnt = 0;
            #define KP(gx, gy, k) { \
                float dx = (gx) - pxs[k]; \
                float dy = (gy) - pys[k]; \
                float d2 = __builtin_fmaf(dx, dx, dy*dy); \
                cnt += (d2 < D2_THRESH) ? 1 : 0; }
            KP(q0.x, q0.y, 0) KP(q0.z, q0.w, 1)
            KP(q1.x, q1.y, 2) KP(q1.z, q1.w, 3)
            KP(q2.x, q2.y, 4) KP(q2.z, q2.w, 5)
            KP(q3.x, q3.y, 6) KP(q3.z, q3.w, 7)
            KP(q4.x, q4.y, 8)
            #undef KP
            // csum can exceed CURMAX_BREAK only if >= 6 kpts close.
            // Exec-masked rare path (P ~ 1e-10 per pair): exact evaluation.
            if (cnt >= CNT_MIN) {
                float csum = 0.0f;
                #define KQ(gx, gy, k) { \
                    float dx = (gx) - pxs[k]; \
                    float dy = (gy) - pys[k]; \
                    float d2 = __builtin_fmaf(dx, dx, dy*dy); \
                    if (d2 < D2_THRESH) \
                        csum += __expf(2.0f - sqrtf(d2) * (2.0f / DIST_THRESH)) - 1.0f; }
                KQ(q0.x, q0.y, 0) KQ(q0.z, q0.w, 1)
                KQ(q1.x, q1.y, 2) KQ(q1.z, q1.w, 3)
                KQ(q2.x, q2.y, 4) KQ(q2.z, q2.w, 5)
                KQ(q3.x, q3.y, 6) KQ(q3.z, q3.w, 7)
                KQ(q4.x, q4.y, 8)
                #undef KQ
                if (csum > CURMAX_BREAK) sil = 1.0f;
            }
        }
    }
    s_sil[wave][cl] = sil;
    __syncthreads();

    // ---- phase 2: wave 0 combines + computes loss ----
    float contrib = 0.0f;
    if (wave == 0 && live) {
        float sl = 0.0f;
        #pragma unroll
        for (int wv = 0; wv < TSPLIT; ++wv) sl = fmaxf(sl, s_sil[wv][cl]);
        const int wn = W[(size_t)b * CELLS + cell];
        const float conf = sigmoidf_(s_ch[18][cl]);

        float cmask, tconf;
        if (wn >= 0) {
            const float* rec = wsf + ((size_t)b * MAX_T + wn) * TREC;
            cmask = OBJECT_SCALE;
            tconf = rec[38];
            #pragma unroll
            for (int k = 0; k < KPT; ++k) {
                // recover raw (xs,ys) from pixel preds: xo = px/SX - w
                float xo = pxs[k] * (1.0f/SX) - (float)w;
                float yo = pys[k] * (1.0f/SY) - (float)h;
                float dxv = xo - rec[20 + 2*k];
                float dyv = yo - rec[21 + 2*k];
                contrib += 0.5f * (dxv*dxv + dyv*dyv);   // COORD_SCALE = 1
            }
        } else {
            cmask = (sl > 0.0f) ? 0.0f : NOOBJECT_SCALE;
            tconf = 0.0f;
        }
        if (epoch_p[0] > PRETRAIN_EPOCHS) {
            float d = conf - tconf;
            contrib += 0.5f * cmask * d * d;
        }
    }

    // ---- wave-0 shuffle reduction + one atomic per block ----
    if (wave == 0) {
        #pragma unroll
        for (int off = 32; off > 0; off >>= 1)
            contrib += __shfl_down(contrib, off);
        if (cl == 0) atomicAdd(d_out, contrib);
    }
}

extern "C" void kernel_launch(void* const* d_in, const int* in_sizes, int n_in,
                              void* d_out, int out_size, void* d_ws, size_t ws_size,
                              hipStream_t stream) {
    const float* output = (const float*)d_in[0];
    const float* target = (const float*)d_in[1];
    const int*   epoch  = (const int*)d_in[2];
    float* out = (float*)d_out;

    float* wsf = (float*)d_ws;
    int*   W   = (int*)(wsf + GT_FLOATS);
    int*   nvA = W + (size_t)NB * CELLS;

    precompute_kernel<<<NB, 512, 0, stream>>>(output, target, wsf, W, nvA, out);

    dim3 grid((CELLS + CPB - 1) / CPB, NB);
    region_loss_kernel<<<grid, NTHREADS, 0, stream>>>(output, wsf, W, nvA, epoch, out);
}